// Round 4
// baseline (477.400 us; speedup 1.0000x reference)
//
#include <hip/hip_runtime.h>
#include <hip/hip_bf16.h>

// Problem constants (fixed by setup_inputs):
//   B=1, T=16384 -> S=16384, C=1280, H=16, D=80, 3C=3840, block=16, nb=1024
// Inputs FP32, output FP32. Workspace budget 222,822,400 B.
#define S_TOK   16384
#define C_DIM   1280
#define C3_DIM  3840
#define H_DIM   16
#define D_DIM   80
#define BLK     16
#define PLANE_ELEMS ((size_t)S_TOK * C_DIM)   // one of Q/K/V planes, elements

using u16x8  = __attribute__((ext_vector_type(8))) unsigned short;
using u16x4  = __attribute__((ext_vector_type(4))) unsigned short;
using bf16x8 = __attribute__((ext_vector_type(8))) __bf16;
using f32x4  = __attribute__((ext_vector_type(4))) float;

__device__ __forceinline__ unsigned short f2bf(float f) {
    return __bfloat16_as_ushort(__float2bfloat16(f));
}
__device__ __forceinline__ float bf2f(unsigned short u) {
    unsigned int x = (unsigned int)u << 16;
    return __builtin_bit_cast(float, x);
}
__device__ __forceinline__ void gload_lds16(const unsigned short* g, unsigned short* l) {
    __builtin_amdgcn_global_load_lds(
        (const __attribute__((address_space(1))) void*)g,
        (__attribute__((address_space(3))) void*)l, 16, 0, 0);
}

// ---------------------------------------------------------------------------
// One-shot weight prep: fp32 W[K][N] -> bf16 W^T[N][K], LDS-tiled.
// ---------------------------------------------------------------------------
__global__ __launch_bounds__(256) void transpose_cvt(
    const float* __restrict__ W, unsigned short* __restrict__ WT, int K, int N)
{
    __shared__ float tile[32][33];
    const int n0 = blockIdx.x * 32, k0 = blockIdx.y * 32;
    const int tx = threadIdx.x & 31, ty = threadIdx.x >> 5;   // 32x8
#pragma unroll
    for (int i = ty; i < 32; i += 8)
        tile[i][tx] = W[(size_t)(k0 + i) * N + n0 + tx];
    __syncthreads();
#pragma unroll
    for (int i = ty; i < 32; i += 8)
        WT[(size_t)(n0 + i) * K + k0 + tx] = f2bf(tile[tx][i]);
}

// ---------------------------------------------------------------------------
// Prepass: xg[s][:] = bf16(x[wi[s]][:]).  (enables global_load_lds in GEMM1)
// ---------------------------------------------------------------------------
__global__ __launch_bounds__(256) void gather_cvt(
    const float* __restrict__ x, const int* __restrict__ wi,
    unsigned short* __restrict__ xg)
{
    int idx = blockIdx.x * 256 + threadIdx.x;   // over S*160 (exact)
    int s  = idx / 160;
    int c8 = (idx - s * 160) * 8;
    const float* src = x + (size_t)wi[s] * C_DIM + c8;
    f32x4 v0 = *(const f32x4*)src;
    f32x4 v1 = *(const f32x4*)(src + 4);
    u16x8 o;
    o[0]=f2bf(v0[0]); o[1]=f2bf(v0[1]); o[2]=f2bf(v0[2]); o[3]=f2bf(v0[3]);
    o[4]=f2bf(v1[0]); o[5]=f2bf(v1[1]); o[6]=f2bf(v1[2]); o[7]=f2bf(v1[3]);
    *(u16x8*)&xg[(size_t)s * C_DIM + c8] = o;
}

// ---------------------------------------------------------------------------
// Tiled bf16 MFMA GEMM, global_load_lds staging + XOR-swizzled LDS.
// (hot loop unchanged — verified 862 TF / 0 bank conflicts)
//
// Epilogue modes:
//   OUTMODE 0: fp32 [M][N]
//   OUTMODE 2: bf16 PLANES [which][h][s][d] (GEMM1; 16-col blocks lie within
//     one (which,head) since 1280%16==0 and 80%16==0).
//   OUTMODE 3: fp32 [M][N] with ROW SCATTER out[row_map[row]] — GEMM2.
//     16 consecutive fp32 lanes = one aligned 64-B full line per store, so
//     the scatter is HBM-friendly; this absorbs the un-permute so attention
//     can store windowed-contiguous.
// ---------------------------------------------------------------------------
#define TM 128
#define TN 128
#define BK 64

template<int OUTMODE>
__global__ __launch_bounds__(256) void gemm_mfma(
    const unsigned short* __restrict__ A,   // [M][K] bf16
    const unsigned short* __restrict__ BT,  // [N][K] bf16
    void* __restrict__ Cp,                  // see OUTMODE
    const int* __restrict__ row_map,        // used iff OUTMODE==3
    int N, int K)
{
    __shared__ __align__(16) unsigned short As[TM * BK];
    __shared__ __align__(16) unsigned short Bs[TN * BK];

    const int m0   = blockIdx.x * TM;
    const int n0   = blockIdx.y * TN;
    const int tid  = threadIdx.x;
    const int lane = tid & 63;
    const int wv   = tid >> 6;
    const int wm   = (wv >> 1) * 64;
    const int wn   = (wv & 1) * 64;
    const int lrow = lane & 15;
    const int quad = lane >> 4;

    int r_[4], csw[4];
#pragma unroll
    for (int c = 0; c < 4; c++) {
        int ch = (wv * 4 + c) * 64 + lane;
        r_[c]  = ch >> 3;                          // 0..127
        csw[c] = ((ch & 7) ^ (r_[c] & 7)) << 3;    // inverse-swizzled col8
    }

    int aoff[4], asw[4], boff[4], bsw[4];
#pragma unroll
    for (int t = 0; t < 4; t++) {
        int ra = wm + t * 16 + lrow;
        aoff[t] = ra << 7;  asw[t] = (ra & 7) << 4;
        int rb = wn + t * 16 + lrow;
        boff[t] = rb << 7;  bsw[t] = (rb & 7) << 4;
    }

    f32x4 acc[4][4];
#pragma unroll
    for (int i = 0; i < 4; i++)
#pragma unroll
        for (int j = 0; j < 4; j++)
            acc[i][j] = (f32x4){0.f, 0.f, 0.f, 0.f};

    for (int kt = 0; kt < K; kt += BK) {
#pragma unroll
        for (int c = 0; c < 4; c++)
            gload_lds16(A + (size_t)(m0 + r_[c]) * K + kt + csw[c],
                        As + (wv * 4 + c) * 512);
#pragma unroll
        for (int c = 0; c < 4; c++)
            gload_lds16(BT + (size_t)(n0 + r_[c]) * K + kt + csw[c],
                        Bs + (wv * 4 + c) * 512);
        __syncthreads();

#pragma unroll
        for (int ks = 0; ks < BK; ks += 32) {
            const int cb = (ks << 1) + (quad << 4);
            bf16x8 af[4], bfr[4];
#pragma unroll
            for (int mt = 0; mt < 4; mt++)
                af[mt] = *(const bf16x8*)((const char*)As +
                                          aoff[mt] + (cb ^ asw[mt]));
#pragma unroll
            for (int nt = 0; nt < 4; nt++)
                bfr[nt] = *(const bf16x8*)((const char*)Bs +
                                           boff[nt] + (cb ^ bsw[nt]));
#pragma unroll
            for (int mt = 0; mt < 4; mt++)
#pragma unroll
                for (int nt = 0; nt < 4; nt++)
                    acc[mt][nt] = __builtin_amdgcn_mfma_f32_16x16x32_bf16(
                        af[mt], bfr[nt], acc[mt][nt], 0, 0, 0);
        }
        __syncthreads();
    }

    // epilogue: D row = quad*4 + r, col = lane&15  (HW-verified C/D layout)
#pragma unroll
    for (int nt = 0; nt < 4; nt++) {
        const int cb = n0 + wn + nt * 16;          // uniform per nt
        unsigned short* pb = nullptr;
        if (OUTMODE == 2) {
            int which = cb / C_DIM;
            int hc    = cb - which * C_DIM;
            int h     = hc / D_DIM;
            int d0    = hc - h * D_DIM;
            pb = (unsigned short*)Cp + (size_t)which * PLANE_ELEMS
               + (size_t)h * S_TOK * D_DIM + d0 + lrow;
        }
#pragma unroll
        for (int mt = 0; mt < 4; mt++)
#pragma unroll
            for (int r = 0; r < 4; r++) {
                int row = m0 + wm + mt * 16 + quad * 4 + r;
                if (OUTMODE == 0)
                    ((float*)Cp)[(size_t)row * N + cb + lrow] = acc[mt][nt][r];
                else if (OUTMODE == 2)
                    pb[(size_t)row * D_DIM] = f2bf(acc[mt][nt][r]);
                else
                    ((float*)Cp)[(size_t)row_map[row] * N + cb + lrow] =
                        acc[mt][nt][r];
            }
    }
}

// ---------------------------------------------------------------------------
// Fused RoPE + block attention v2: one WAVE per (block b, head h), LDS-staged.
//
// R3's version was ~185 us: 40 scalar V gathers + 12 cos/sin loads x 16
// scattered rows + 5 stores x 16 scattered rows per wave = segment-count-
// bound. v2 eliminates every scattered class:
//   - V: 3x global_load_lds (16 B/lane, coalesced) into a per-wave LDS slot
//     (no __syncthreads needed; vmcnt(0) only).
//   - Q/K: reg-staged coalesced WITH RoPE fused: staging chunk (row,d0..d7)
//     needs cos/sin[crow(row)][d0..d7] = contiguous 32 B per lane.
//     Rotated bf16 Q',K' written to LDS [16][88] (stride-88: rows r,r+8
//     alias = 2-way = free).
//   - fragments from LDS: 6x ds_read_b128 (Q,K) + 40x ds_read_u16 (V^T).
//   - output written to yw in WINDOWED order (16-consecutive-row block per
//     WG, contiguous); the un-permute moved to GEMM2's full-line scatter.
//
// mfma conventions (same as verified gemm): A/B frag lane -> [lane&15][quad*8+e];
// C: lane holds C[quad*4+r][lane&15]. QK^T swapped: mfma(K',Q') ->
// S[q=lane&15][k=quad*4+r]; softmax = 4 in-reg ops + shfl_xor(16,32).
// PV: mfma(V^T, P); P unnormalized bf16 (e<=1), 1/sum applied fp32 at store.
// K-pad k>=16 of the K=32 MFMA: P-side fragment zeroed (V side then reads
// real finite rows, product is exactly 0 -- no NaN risk).
// ---------------------------------------------------------------------------
__global__ __launch_bounds__(256) void attn_v2(
    const unsigned short* __restrict__ planes,  // [3][H][S][D] bf16
    const float* __restrict__ cosp,
    const float* __restrict__ sinp,
    const int* __restrict__ wi,
    unsigned short* __restrict__ yw)            // [S][1280] bf16, WINDOWED
{
    __shared__ __align__(16) unsigned short Q_lds[4][16][88];
    __shared__ __align__(16) unsigned short K_lds[4][16][88];
    __shared__ __align__(16) unsigned short V_lds[4][1536]; // 2560B data+512 slack

    const int wave = threadIdx.x >> 6;
    const int lane = threadIdx.x & 63;
    const int b    = blockIdx.y;
    const int h    = blockIdx.x * 4 + wave;   // 4 heads per WG
    const int j16  = lane & 15;
    const int quad = lane >> 4;

    // ---- V: async DMA to per-wave LDS slot, issued first ----
    const unsigned short* Vsrc = planes + 2 * PLANE_ELEMS
        + ((size_t)h * S_TOK + b * BLK) * D_DIM;
    unsigned short* Vsl = &V_lds[wave][0];
#pragma unroll
    for (int c = 0; c < 3; c++)                 // 3 KB staged (2.5 KB real)
        gload_lds16(Vsrc + c * 512 + lane * 8, Vsl + c * 512);

    // ---- Q/K: reg-staged coalesced, RoPE fused, bf16 to LDS ----
    const unsigned short* Qbase = planes + ((size_t)h * S_TOK + b * BLK) * D_DIM;
#pragma unroll
    for (int c = 0; c < 3; c++) {
        int ch = c * 64 + lane;                 // chunk over 16 rows x 10
        if (ch < 160) {
            int r  = ch / 10;                   // 0..15
            int d8 = (ch - r * 10) * 8;         // 0..72
            int crow = wi[b * BLK + r];
            const unsigned short* Qp = Qbase + (size_t)r * D_DIM + d8;
            u16x8 qv = *(const u16x8*)Qp;
            u16x8 kv = *(const u16x8*)(Qp + PLANE_ELEMS);
            const float* cp = cosp + (size_t)crow * D_DIM + d8;
            const float* sp = sinp + (size_t)crow * D_DIM + d8;
            f32x4 c0 = *(const f32x4*)cp, c1 = *(const f32x4*)(cp + 4);
            f32x4 s0 = *(const f32x4*)sp, s1 = *(const f32x4*)(sp + 4);
            u16x8 qo, ko;
#pragma unroll
            for (int j = 0; j < 8; j++) {
                float cw = (j < 4) ? c0[j] : c1[j - 4];
                float sw = (j < 4) ? s0[j] : s1[j - 4];
                float q = bf2f(qv[j]), k = bf2f(kv[j]);
                qo[j] = f2bf(q * cw + k * sw);
                ko[j] = f2bf(k * cw - q * sw);
            }
            *(u16x8*)&Q_lds[wave][r][d8] = qo;
            *(u16x8*)&K_lds[wave][r][d8] = ko;
        }
    }

    // V DMA completion (per-wave slot: no barrier, just drain the queue).
    asm volatile("s_waitcnt vmcnt(0)" ::: "memory");
    __builtin_amdgcn_sched_barrier(0);

    // ---- Q/K fragments from LDS ----
    const u16x8 zz = {0, 0, 0, 0, 0, 0, 0, 0};
    bf16x8 qf[3], kf[3];
#pragma unroll
    for (int s = 0; s < 3; s++) {
        int dcol = 32 * s + quad * 8;
        bool pad = (dcol >= D_DIM);             // s==2, quad>=2 -> k-pad
        int dc = pad ? 0 : dcol;
        u16x8 qv = *(const u16x8*)&Q_lds[wave][j16][dc];
        u16x8 kv = *(const u16x8*)&K_lds[wave][j16][dc];
        if (pad) { qv = zz; kv = zz; }
        qf[s] = __builtin_bit_cast(bf16x8, qv);
        kf[s] = __builtin_bit_cast(bf16x8, kv);
    }

    // ---- scores: S[q=lane&15][k=quad*4+r] ----
    f32x4 sacc = (f32x4){0.f, 0.f, 0.f, 0.f};
#pragma unroll
    for (int s = 0; s < 3; s++)
        sacc = __builtin_amdgcn_mfma_f32_16x16x32_bf16(kf[s], qf[s], sacc, 0, 0, 0);

    // ---- softmax over k ----
    const float scale = 0.11180339887498948f;   // 1/sqrt(80)
    float sc[4];
#pragma unroll
    for (int r = 0; r < 4; r++) sc[r] = sacc[r] * scale;
    float m = fmaxf(fmaxf(sc[0], sc[1]), fmaxf(sc[2], sc[3]));
    m = fmaxf(m, __shfl_xor(m, 16));
    m = fmaxf(m, __shfl_xor(m, 32));
    float e[4], sum = 0.f;
#pragma unroll
    for (int r = 0; r < 4; r++) { e[r] = __expf(sc[r] - m); sum += e[r]; }
    sum += __shfl_xor(sum, 16);
    sum += __shfl_xor(sum, 32);
    float inv = 1.f / sum;

    // ---- P fragment (B-operand): lane needs P[j16][quad*8+e] ----
    int sl = quad * 32 + j16;                   // valid for quad<2
    float pv0[4], pv1[4];
#pragma unroll
    for (int r = 0; r < 4; r++) pv0[r] = __shfl(e[r], sl & 63);
#pragma unroll
    for (int r = 0; r < 4; r++) pv1[r] = __shfl(e[r], (sl + 16) & 63);
    u16x8 pf;
#pragma unroll
    for (int r = 0; r < 4; r++) {
        pf[r]     = (quad < 2) ? f2bf(pv0[r]) : (unsigned short)0;
        pf[r + 4] = (quad < 2) ? f2bf(pv1[r]) : (unsigned short)0;
    }
    bf16x8 pfrag = __builtin_bit_cast(bf16x8, pf);

    // ---- V^T fragments from LDS: lane supplies V[quad*8+e][t*16+j16] ----
    // quads 2,3 (k-pad) read row e (real, finite); product zeroed by pfrag.
    u16x8 vf[5];
#pragma unroll
    for (int t = 0; t < 5; t++) {
#pragma unroll
        for (int e8 = 0; e8 < 8; e8++) {
            int kks = quad * 8 + e8;
            if (kks >= BLK) kks = e8;
            vf[t][e8] = Vsl[kks * D_DIM + t * 16 + j16];
        }
    }

    // ---- PV + normalize + CONTIGUOUS windowed store ----
    unsigned short* yrow = yw + (size_t)(b * BLK + j16) * C_DIM
                         + h * D_DIM + quad * 4;
#pragma unroll
    for (int t = 0; t < 5; t++) {
        f32x4 o = __builtin_amdgcn_mfma_f32_16x16x32_bf16(
            __builtin_bit_cast(bf16x8, vf[t]), pfrag,
            (f32x4){0.f, 0.f, 0.f, 0.f}, 0, 0, 0);
        u16x4 ov;
#pragma unroll
        for (int r = 0; r < 4; r++) ov[r] = f2bf(o[r] * inv);
        *(u16x4*)(yrow + t * 16) = ov;
    }
}

extern "C" void kernel_launch(void* const* d_in, const int* in_sizes, int n_in,
                              void* d_out, int out_size, void* d_ws, size_t ws_size,
                              hipStream_t stream)
{
    const float* x     = (const float*)d_in[0];
    const float* cosp  = (const float*)d_in[1];
    const float* sinp  = (const float*)d_in[2];
    const float* Wqkv  = (const float*)d_in[3];
    const float* Wproj = (const float*)d_in[4];
    const int*   wi    = (const int*)d_in[5];

    // workspace layout (bytes):
    //   qkv planes @ 0        : S*3840*2    = 125,829,120  ([3][H][S][D])
    //   yw     @ 125829120    : S*1280*2    =  41,943,040  (windowed order)
    //   wqkvT  @ 167772160    : 3840*1280*2 =   9,830,400   (bf16 [N][K])
    //   wprojT @ 177602560    : 1280*1280*2 =   3,276,800   (bf16 [N][K])
    //   xg     @ 180879360    : S*1280*2    =  41,943,040   (bf16 gathered x)
    char* ws = (char*)d_ws;
    unsigned short* planes = (unsigned short*)ws;
    unsigned short* yw     = (unsigned short*)(ws + 125829120ull);
    unsigned short* wqkvT  = (unsigned short*)(ws + 167772160ull);
    unsigned short* wprojT = (unsigned short*)(ws + 177602560ull);
    unsigned short* xg     = (unsigned short*)(ws + 180879360ull);

    // 0) weight prep: fp32 [K][N] -> bf16 [N][K]
    transpose_cvt<<<dim3(C3_DIM / 32, C_DIM / 32), 256, 0, stream>>>(
        Wqkv, wqkvT, C_DIM, C3_DIM);
    transpose_cvt<<<dim3(C_DIM / 32, C_DIM / 32), 256, 0, stream>>>(
        Wproj, wprojT, C_DIM, C_DIM);

    // 0b) gather + cvt prepass: xg[s] = bf16(x[wi[s]])
    gather_cvt<<<S_TOK * 160 / 256, 256, 0, stream>>>(x, wi, xg);

    // 1) qkv = xg @ W_qkv, written as [3][H][S][D] planes (rope fused in attn)
    gemm_mfma<2><<<dim3(S_TOK / TM, C3_DIM / TN), 256, 0, stream>>>(
        xg, wqkvT, planes, nullptr, C3_DIM, C_DIM);

    // 2) fused rope + block attention; output in WINDOWED order (contiguous)
    attn_v2<<<dim3(H_DIM / 4, S_TOK / BLK), 256, 0, stream>>>(
        planes, cosp, sinp, wi, yw);

    // 3) out[wi[row]] = (yw @ W_proj)[row] -> fp32 d_out (full-line scatter)
    gemm_mfma<3><<<dim3(S_TOK / TM, C_DIM / TN), 256, 0, stream>>>(
        yw, wprojT, d_out, wi, C_DIM, C_DIM);
}

// Round 5
// 464.487 us; speedup vs baseline: 1.0278x; 1.0278x over previous
//
#include <hip/hip_runtime.h>
#include <hip/hip_bf16.h>

// Problem constants (fixed by setup_inputs):
//   B=1, T=16384 -> S=16384, C=1280, H=16, D=80, 3C=3840, block=16, nb=1024
// Inputs FP32, output FP32. Workspace budget 222,822,400 B.
#define S_TOK   16384
#define C_DIM   1280
#define C3_DIM  3840
#define H_DIM   16
#define D_DIM   80
#define BLK     16
#define PLANE_ELEMS ((size_t)S_TOK * C_DIM)   // one of Q/K/V planes, elements

using u16x8  = __attribute__((ext_vector_type(8))) unsigned short;
using u16x4  = __attribute__((ext_vector_type(4))) unsigned short;
using bf16x8 = __attribute__((ext_vector_type(8))) __bf16;
using f32x4  = __attribute__((ext_vector_type(4))) float;

__device__ __forceinline__ unsigned short f2bf(float f) {
    return __bfloat16_as_ushort(__float2bfloat16(f));
}
__device__ __forceinline__ float bf2f(unsigned short u) {
    unsigned int x = (unsigned int)u << 16;
    return __builtin_bit_cast(float, x);
}
__device__ __forceinline__ void gload_lds16(const unsigned short* g, unsigned short* l) {
    __builtin_amdgcn_global_load_lds(
        (const __attribute__((address_space(1))) void*)g,
        (__attribute__((address_space(3))) void*)l, 16, 0, 0);
}

// ---------------------------------------------------------------------------
// One-shot weight prep: fp32 W[K][N] -> bf16 W^T[N][K], LDS-tiled.
// ---------------------------------------------------------------------------
__global__ __launch_bounds__(256) void transpose_cvt(
    const float* __restrict__ W, unsigned short* __restrict__ WT, int K, int N)
{
    __shared__ float tile[32][33];
    const int n0 = blockIdx.x * 32, k0 = blockIdx.y * 32;
    const int tx = threadIdx.x & 31, ty = threadIdx.x >> 5;   // 32x8
#pragma unroll
    for (int i = ty; i < 32; i += 8)
        tile[i][tx] = W[(size_t)(k0 + i) * N + n0 + tx];
    __syncthreads();
#pragma unroll
    for (int i = ty; i < 32; i += 8)
        WT[(size_t)(n0 + i) * K + k0 + tx] = f2bf(tile[tx][i]);
}

// ---------------------------------------------------------------------------
// Prepass: xg[s][:] = bf16(x[wi[s]][:]).  (enables global_load_lds in GEMM1)
// ---------------------------------------------------------------------------
__global__ __launch_bounds__(256) void gather_cvt(
    const float* __restrict__ x, const int* __restrict__ wi,
    unsigned short* __restrict__ xg)
{
    int idx = blockIdx.x * 256 + threadIdx.x;   // over S*160 (exact)
    int s  = idx / 160;
    int c8 = (idx - s * 160) * 8;
    const float* src = x + (size_t)wi[s] * C_DIM + c8;
    f32x4 v0 = *(const f32x4*)src;
    f32x4 v1 = *(const f32x4*)(src + 4);
    u16x8 o;
    o[0]=f2bf(v0[0]); o[1]=f2bf(v0[1]); o[2]=f2bf(v0[2]); o[3]=f2bf(v0[3]);
    o[4]=f2bf(v1[0]); o[5]=f2bf(v1[1]); o[6]=f2bf(v1[2]); o[7]=f2bf(v1[3]);
    *(u16x8*)&xg[(size_t)s * C_DIM + c8] = o;
}

// ---------------------------------------------------------------------------
// Inverse permutation: inv[wi[s]] = s.  (argsort of a permutation)
// ---------------------------------------------------------------------------
__global__ __launch_bounds__(256) void inv_perm(
    const int* __restrict__ wi, int* __restrict__ inv)
{
    int s = blockIdx.x * 256 + threadIdx.x;
    inv[wi[s]] = s;
}

// ---------------------------------------------------------------------------
// Tiled bf16 MFMA GEMM, global_load_lds staging + XOR-swizzled LDS.
// (hot loop unchanged — verified 862 TF / 0 bank conflicts)
//
//   OUTMODE 0: fp32 [M][N] contiguous
//   OUTMODE 2: bf16 PLANES [which][h][s][d] (GEMM1)
//   GATHER: A-row gather via row_map (GEMM2 un-permute — READ-side, so each
//     global_load_lds still covers 8 rows x 128 contiguous B; no RMW, no
//     write amplification. R4's write-side scatter cost 136 us.)
// ---------------------------------------------------------------------------
#define TM 128
#define TN 128
#define BK 64

template<int OUTMODE, bool GATHER>
__global__ __launch_bounds__(256) void gemm_mfma(
    const unsigned short* __restrict__ A,   // [M][K] bf16
    const unsigned short* __restrict__ BT,  // [N][K] bf16
    void* __restrict__ Cp,                  // see OUTMODE
    const int* __restrict__ row_map,        // used iff GATHER
    int N, int K)
{
    __shared__ __align__(16) unsigned short As[TM * BK];
    __shared__ __align__(16) unsigned short Bs[TN * BK];

    const int m0   = blockIdx.x * TM;
    const int n0   = blockIdx.y * TN;
    const int tid  = threadIdx.x;
    const int lane = tid & 63;
    const int wv   = tid >> 6;
    const int wm   = (wv >> 1) * 64;
    const int wn   = (wv & 1) * 64;
    const int lrow = lane & 15;
    const int quad = lane >> 4;

    int gr[4], nr[4], csw[4];
#pragma unroll
    for (int c = 0; c < 4; c++) {
        int ch = (wv * 4 + c) * 64 + lane;
        int r  = ch >> 3;                          // 0..127
        csw[c] = ((ch & 7) ^ (r & 7)) << 3;        // inverse-swizzled col8
        gr[c]  = GATHER ? row_map[m0 + r] : (m0 + r);   // hoisted out of K-loop
        nr[c]  = n0 + r;
    }

    int aoff[4], asw[4], boff[4], bsw[4];
#pragma unroll
    for (int t = 0; t < 4; t++) {
        int ra = wm + t * 16 + lrow;
        aoff[t] = ra << 7;  asw[t] = (ra & 7) << 4;
        int rb = wn + t * 16 + lrow;
        boff[t] = rb << 7;  bsw[t] = (rb & 7) << 4;
    }

    f32x4 acc[4][4];
#pragma unroll
    for (int i = 0; i < 4; i++)
#pragma unroll
        for (int j = 0; j < 4; j++)
            acc[i][j] = (f32x4){0.f, 0.f, 0.f, 0.f};

    for (int kt = 0; kt < K; kt += BK) {
#pragma unroll
        for (int c = 0; c < 4; c++)
            gload_lds16(A + (size_t)gr[c] * K + kt + csw[c],
                        As + (wv * 4 + c) * 512);
#pragma unroll
        for (int c = 0; c < 4; c++)
            gload_lds16(BT + (size_t)nr[c] * K + kt + csw[c],
                        Bs + (wv * 4 + c) * 512);
        __syncthreads();

#pragma unroll
        for (int ks = 0; ks < BK; ks += 32) {
            const int cb = (ks << 1) + (quad << 4);
            bf16x8 af[4], bfr[4];
#pragma unroll
            for (int mt = 0; mt < 4; mt++)
                af[mt] = *(const bf16x8*)((const char*)As +
                                          aoff[mt] + (cb ^ asw[mt]));
#pragma unroll
            for (int nt = 0; nt < 4; nt++)
                bfr[nt] = *(const bf16x8*)((const char*)Bs +
                                           boff[nt] + (cb ^ bsw[nt]));
#pragma unroll
            for (int mt = 0; mt < 4; mt++)
#pragma unroll
                for (int nt = 0; nt < 4; nt++)
                    acc[mt][nt] = __builtin_amdgcn_mfma_f32_16x16x32_bf16(
                        af[mt], bfr[nt], acc[mt][nt], 0, 0, 0);
        }
        __syncthreads();
    }

    // epilogue: D row = quad*4 + r, col = lane&15  (HW-verified C/D layout)
#pragma unroll
    for (int nt = 0; nt < 4; nt++) {
        const int cb = n0 + wn + nt * 16;          // uniform per nt
        unsigned short* pb = nullptr;
        if (OUTMODE == 2) {
            int which = cb / C_DIM;
            int hc    = cb - which * C_DIM;
            int h     = hc / D_DIM;
            int d0    = hc - h * D_DIM;
            pb = (unsigned short*)Cp + (size_t)which * PLANE_ELEMS
               + (size_t)h * S_TOK * D_DIM + d0 + lrow;
        }
#pragma unroll
        for (int mt = 0; mt < 4; mt++)
#pragma unroll
            for (int r = 0; r < 4; r++) {
                int row = m0 + wm + mt * 16 + quad * 4 + r;
                if (OUTMODE == 0)
                    ((float*)Cp)[(size_t)row * N + cb + lrow] = acc[mt][nt][r];
                else
                    pb[(size_t)row * D_DIM] = f2bf(acc[mt][nt][r]);
            }
    }
}

// ---------------------------------------------------------------------------
// Fused RoPE + block attention v2 (unchanged from R4 — worked: ~50 us).
// One WAVE per (block b, head h), LDS-staged, all accesses coalesced,
// output in WINDOWED order (contiguous); un-permute absorbed by GEMM2's
// A-row gather.
// ---------------------------------------------------------------------------
__global__ __launch_bounds__(256) void attn_v2(
    const unsigned short* __restrict__ planes,  // [3][H][S][D] bf16
    const float* __restrict__ cosp,
    const float* __restrict__ sinp,
    const int* __restrict__ wi,
    unsigned short* __restrict__ yw)            // [S][1280] bf16, WINDOWED
{
    __shared__ __align__(16) unsigned short Q_lds[4][16][88];
    __shared__ __align__(16) unsigned short K_lds[4][16][88];
    __shared__ __align__(16) unsigned short V_lds[4][1536]; // 2560B data+512 slack

    const int wave = threadIdx.x >> 6;
    const int lane = threadIdx.x & 63;
    const int b    = blockIdx.y;
    const int h    = blockIdx.x * 4 + wave;   // 4 heads per WG
    const int j16  = lane & 15;
    const int quad = lane >> 4;

    // ---- V: async DMA to per-wave LDS slot, issued first ----
    const unsigned short* Vsrc = planes + 2 * PLANE_ELEMS
        + ((size_t)h * S_TOK + b * BLK) * D_DIM;
    unsigned short* Vsl = &V_lds[wave][0];
#pragma unroll
    for (int c = 0; c < 3; c++)                 // 3 KB staged (2.5 KB real)
        gload_lds16(Vsrc + c * 512 + lane * 8, Vsl + c * 512);

    // ---- Q/K: reg-staged coalesced, RoPE fused, bf16 to LDS ----
    const unsigned short* Qbase = planes + ((size_t)h * S_TOK + b * BLK) * D_DIM;
#pragma unroll
    for (int c = 0; c < 3; c++) {
        int ch = c * 64 + lane;                 // chunk over 16 rows x 10
        if (ch < 160) {
            int r  = ch / 10;                   // 0..15
            int d8 = (ch - r * 10) * 8;         // 0..72
            int crow = wi[b * BLK + r];
            const unsigned short* Qp = Qbase + (size_t)r * D_DIM + d8;
            u16x8 qv = *(const u16x8*)Qp;
            u16x8 kv = *(const u16x8*)(Qp + PLANE_ELEMS);
            const float* cp = cosp + (size_t)crow * D_DIM + d8;
            const float* sp = sinp + (size_t)crow * D_DIM + d8;
            f32x4 c0 = *(const f32x4*)cp, c1 = *(const f32x4*)(cp + 4);
            f32x4 s0 = *(const f32x4*)sp, s1 = *(const f32x4*)(sp + 4);
            u16x8 qo, ko;
#pragma unroll
            for (int j = 0; j < 8; j++) {
                float cw = (j < 4) ? c0[j] : c1[j - 4];
                float sw = (j < 4) ? s0[j] : s1[j - 4];
                float q = bf2f(qv[j]), k = bf2f(kv[j]);
                qo[j] = f2bf(q * cw + k * sw);
                ko[j] = f2bf(k * cw - q * sw);
            }
            *(u16x8*)&Q_lds[wave][r][d8] = qo;
            *(u16x8*)&K_lds[wave][r][d8] = ko;
        }
    }

    // V DMA completion (per-wave slot: no barrier, just drain the queue).
    asm volatile("s_waitcnt vmcnt(0)" ::: "memory");
    __builtin_amdgcn_sched_barrier(0);

    // ---- Q/K fragments from LDS ----
    const u16x8 zz = {0, 0, 0, 0, 0, 0, 0, 0};
    bf16x8 qf[3], kf[3];
#pragma unroll
    for (int s = 0; s < 3; s++) {
        int dcol = 32 * s + quad * 8;
        bool pad = (dcol >= D_DIM);             // s==2, quad>=2 -> k-pad
        int dc = pad ? 0 : dcol;
        u16x8 qv = *(const u16x8*)&Q_lds[wave][j16][dc];
        u16x8 kv = *(const u16x8*)&K_lds[wave][j16][dc];
        if (pad) { qv = zz; kv = zz; }
        qf[s] = __builtin_bit_cast(bf16x8, qv);
        kf[s] = __builtin_bit_cast(bf16x8, kv);
    }

    // ---- scores: S[q=lane&15][k=quad*4+r] ----
    f32x4 sacc = (f32x4){0.f, 0.f, 0.f, 0.f};
#pragma unroll
    for (int s = 0; s < 3; s++)
        sacc = __builtin_amdgcn_mfma_f32_16x16x32_bf16(kf[s], qf[s], sacc, 0, 0, 0);

    // ---- softmax over k ----
    const float scale = 0.11180339887498948f;   // 1/sqrt(80)
    float sc[4];
#pragma unroll
    for (int r = 0; r < 4; r++) sc[r] = sacc[r] * scale;
    float m = fmaxf(fmaxf(sc[0], sc[1]), fmaxf(sc[2], sc[3]));
    m = fmaxf(m, __shfl_xor(m, 16));
    m = fmaxf(m, __shfl_xor(m, 32));
    float e[4], sum = 0.f;
#pragma unroll
    for (int r = 0; r < 4; r++) { e[r] = __expf(sc[r] - m); sum += e[r]; }
    sum += __shfl_xor(sum, 16);
    sum += __shfl_xor(sum, 32);
    float inv = 1.f / sum;

    // ---- P fragment (B-operand): lane needs P[j16][quad*8+e] ----
    int sl = quad * 32 + j16;                   // valid for quad<2
    float pv0[4], pv1[4];
#pragma unroll
    for (int r = 0; r < 4; r++) pv0[r] = __shfl(e[r], sl & 63);
#pragma unroll
    for (int r = 0; r < 4; r++) pv1[r] = __shfl(e[r], (sl + 16) & 63);
    u16x8 pf;
#pragma unroll
    for (int r = 0; r < 4; r++) {
        pf[r]     = (quad < 2) ? f2bf(pv0[r]) : (unsigned short)0;
        pf[r + 4] = (quad < 2) ? f2bf(pv1[r]) : (unsigned short)0;
    }
    bf16x8 pfrag = __builtin_bit_cast(bf16x8, pf);

    // ---- V^T fragments from LDS: lane supplies V[quad*8+e][t*16+j16] ----
    u16x8 vf[5];
#pragma unroll
    for (int t = 0; t < 5; t++) {
#pragma unroll
        for (int e8 = 0; e8 < 8; e8++) {
            int kks = quad * 8 + e8;
            if (kks >= BLK) kks = e8;           // pad quads: zeroed by pfrag
            vf[t][e8] = Vsl[kks * D_DIM + t * 16 + j16];
        }
    }

    // ---- PV + normalize + CONTIGUOUS windowed store ----
    unsigned short* yrow = yw + (size_t)(b * BLK + j16) * C_DIM
                         + h * D_DIM + quad * 4;
#pragma unroll
    for (int t = 0; t < 5; t++) {
        f32x4 o = __builtin_amdgcn_mfma_f32_16x16x32_bf16(
            __builtin_bit_cast(bf16x8, vf[t]), pfrag,
            (f32x4){0.f, 0.f, 0.f, 0.f}, 0, 0, 0);
        u16x4 ov;
#pragma unroll
        for (int r = 0; r < 4; r++) ov[r] = f2bf(o[r] * inv);
        *(u16x4*)(yrow + t * 16) = ov;
    }
}

extern "C" void kernel_launch(void* const* d_in, const int* in_sizes, int n_in,
                              void* d_out, int out_size, void* d_ws, size_t ws_size,
                              hipStream_t stream)
{
    const float* x     = (const float*)d_in[0];
    const float* cosp  = (const float*)d_in[1];
    const float* sinp  = (const float*)d_in[2];
    const float* Wqkv  = (const float*)d_in[3];
    const float* Wproj = (const float*)d_in[4];
    const int*   wi    = (const int*)d_in[5];

    // workspace layout (bytes):
    //   qkv planes @ 0        : S*3840*2    = 125,829,120  ([3][H][S][D])
    //   yw     @ 125829120    : S*1280*2    =  41,943,040  (windowed order)
    //   wqkvT  @ 167772160    : 3840*1280*2 =   9,830,400   (bf16 [N][K])
    //   wprojT @ 177602560    : 1280*1280*2 =   3,276,800   (bf16 [N][K])
    //   xg     @ 180879360    : S*1280*2    =  41,943,040   (bf16 gathered x)
    //   inv    @ 180879360    : S*4 = 65,536 — ALIASES xg; written only after
    //     GEMM1 has consumed xg (stream-ordered).
    char* ws = (char*)d_ws;
    unsigned short* planes = (unsigned short*)ws;
    unsigned short* yw     = (unsigned short*)(ws + 125829120ull);
    unsigned short* wqkvT  = (unsigned short*)(ws + 167772160ull);
    unsigned short* wprojT = (unsigned short*)(ws + 177602560ull);
    unsigned short* xg     = (unsigned short*)(ws + 180879360ull);
    int*            inv    = (int*)(ws + 180879360ull);

    // 0) weight prep: fp32 [K][N] -> bf16 [N][K]
    transpose_cvt<<<dim3(C3_DIM / 32, C_DIM / 32), 256, 0, stream>>>(
        Wqkv, wqkvT, C_DIM, C3_DIM);
    transpose_cvt<<<dim3(C_DIM / 32, C_DIM / 32), 256, 0, stream>>>(
        Wproj, wprojT, C_DIM, C_DIM);

    // 0b) gather + cvt prepass: xg[s] = bf16(x[wi[s]])
    gather_cvt<<<S_TOK * 160 / 256, 256, 0, stream>>>(x, wi, xg);

    // 1) qkv = xg @ W_qkv, written as [3][H][S][D] planes (rope fused in attn)
    gemm_mfma<2, false><<<dim3(S_TOK / TM, C3_DIM / TN), 256, 0, stream>>>(
        xg, wqkvT, planes, nullptr, C3_DIM, C_DIM);

    // 1b) inverse permutation (xg is dead now; reuse its space)
    inv_perm<<<S_TOK / 256, 256, 0, stream>>>(wi, inv);

    // 2) fused rope + block attention; output in WINDOWED order (contiguous)
    attn_v2<<<dim3(H_DIM / 4, S_TOK / BLK), 256, 0, stream>>>(
        planes, cosp, sinp, wi, yw);

    // 3) out[r'] = yw[inv[r']] @ W_proj -> fp32 d_out, contiguous writes;
    //    un-permute rides the A-row gather (read-side, full segments).
    gemm_mfma<0, true><<<dim3(S_TOK / TM, C_DIM / TN), 256, 0, stream>>>(
        yw, wprojT, d_out, inv, C_DIM, C_DIM);
}